// Round 2
// baseline (132.913 us; speedup 1.0000x reference)
//
#include <hip/hip_runtime.h>
#include <hip/hip_bf16.h>

using short4v = __attribute__((ext_vector_type(4))) short;
using short8  = __attribute__((ext_vector_type(8))) short;
using uint2v  = __attribute__((ext_vector_type(2))) unsigned int;
using f32x4   = __attribute__((ext_vector_type(4))) float;

static constexpr int CDIM = 512;
static constexpr float KSCALE = 0.125f * 1.44269504088896341f;  // scale*log2(e), folded into Q

// proven RNE convert (rounds 2-5)
__device__ __forceinline__ short f2bf(float f) {
  unsigned u = __builtin_bit_cast(unsigned, f);
  u = (u + 0x7fffu + ((u >> 16) & 1u)) >> 16;
  return (short)(unsigned short)u;
}
__device__ __forceinline__ unsigned pack_bf16(float a, float b) {
  return (unsigned)(unsigned short)f2bf(a) | ((unsigned)(unsigned short)f2bf(b) << 16);
}

#define GLOAD_LDS16(gp, lp)                                                              \
  __builtin_amdgcn_global_load_lds((const __attribute__((address_space(1))) void*)(gp),  \
                                   (__attribute__((address_space(3))) void*)(lp), 16, 0, 0)
#define MFMA16(a, b, c) __builtin_amdgcn_mfma_f32_16x16x32_bf16((a), (b), (c), 0, 0, 0)

// Hardened intra-wave LDS fence (rule #18 class): IR fence + lgkmcnt drain +
// machine-scheduler fence. Zero extra instructions beyond the waitcnt.
#define LDS_FENCE()                        \
  do {                                     \
    asm volatile("" ::: "memory");         \
    __builtin_amdgcn_s_waitcnt(0xc07f);    \
    __builtin_amdgcn_sched_barrier(0);     \
  } while (0)

// Pipeline sync (T4): wait for the CURRENT tile's staged loads only -- counted
// vmcnt, never 0 in steady state -- then block barrier. Fences on both sides.
#define TILE_SYNC(N)                                          \
  do {                                                        \
    __builtin_amdgcn_sched_barrier(0);                        \
    asm volatile("s_waitcnt vmcnt(" #N ")" ::: "memory");     \
    __builtin_amdgcn_sched_barrier(0);                        \
    __builtin_amdgcn_s_barrier();                             \
    asm volatile("" ::: "memory");                            \
    __builtin_amdgcn_sched_barrier(0);                        \
  } while (0)

// End-of-tile barrier: drain this wave's LDS reads (lgkmcnt only -- the
// in-flight vmcnt prefetch deliberately stays live across the barrier),
// then block barrier so no wave overwrites a buffer still being read.
#define TILE_BAR()                                            \
  do {                                                        \
    __builtin_amdgcn_sched_barrier(0);                        \
    asm volatile("s_waitcnt lgkmcnt(0)" ::: "memory");        \
    __builtin_amdgcn_sched_barrier(0);                        \
    __builtin_amdgcn_s_barrier();                             \
    asm volatile("" ::: "memory");                            \
    __builtin_amdgcn_sched_barrier(0);                        \
  } while (0)

// ---- fused cast+transpose for Q, KV, W in ONE launch ----
__global__ __launch_bounds__(256) void prep_transpose(const float* __restrict__ query,
                                                      const float* __restrict__ keyv,
                                                      const float* __restrict__ Wqkv,
                                                      short* __restrict__ Xq_t,
                                                      short* __restrict__ Xkv_t,
                                                      short* __restrict__ W_t) {
  __shared__ float tile[64 * 65];
  const int id = blockIdx.x;
  const float* s; short* d; int R, C, r0, c0;
  if (id < 2048) {
    const int which = id >> 10;
    int rem = id & 1023;
    const int b = rem >> 7; rem &= 127;
    R = 512; C = 1024;
    s = (which ? keyv : query) + (size_t)b * 512 * 1024;
    d = (which ? Xkv_t : Xq_t) + (size_t)b * 512 * 1024;
    r0 = (rem >> 4) * 64; c0 = (rem & 15) * 64;
  } else {
    const int rem = id - 2048;                 // 0..191
    R = 512; C = 1536; s = Wqkv; d = W_t;
    r0 = (rem / 24) * 64; c0 = (rem % 24) * 64;
  }
  const int t  = threadIdx.x;
  const int rr = t >> 4;
  const int c4 = (t & 15) * 4;
#pragma unroll
  for (int i = 0; i < 4; ++i) {
    const int r = rr + i * 16;
    f32x4 v = *(const f32x4*)(s + (size_t)(r0 + r) * C + c0 + c4);
#pragma unroll
    for (int j = 0; j < 4; ++j) tile[(c4 + j) * 65 + r] = v[j];
  }
  __syncthreads();
  const int r8 = (t & 7) * 8;
#pragma unroll
  for (int i = 0; i < 2; ++i) {
    const int c = (t >> 3) + i * 32;
    short8 pk;
#pragma unroll
    for (int j = 0; j < 8; ++j) pk[j] = f2bf(tile[c * 65 + r8 + j]);
    *(short8*)(d + (size_t)(c0 + c) * R + r0 + r8) = pk;
  }
}

// ---- QKV projection, BM=128 BN=256 BK=64, swizzled LDS, XCD-clustered grid ----
//   Qg,Kg: [bh][s][d] (Q pre-scaled by KSCALE), Vt: [bh][d][s]
__global__ __launch_bounds__(256, 2) void qkv_gemm(const short* __restrict__ Xq,
                                                   const short* __restrict__ Xkv,
                                                   const short* __restrict__ Wt,
                                                   const float* __restrict__ bias,
                                                   short* __restrict__ Qg,
                                                   short* __restrict__ Kg,
                                                   short* __restrict__ Vt) {
  __shared__ short Asm[128 * 64];               // slot(row,u) holds chunk u^(row&7)
  __shared__ short Bsm[256 * 64];
  __shared__ short epi[4 * 1152];
  // XCD clustering (bijective id permutation): id&7 = XCD; each XCD slice owns
  // 8 m-tiles x all 6 n-tiles -> A slice (1MB) + W (1.5MB) L2-resident.
  const int id = blockIdx.x;
  const int n_blk = id >> 6;
  const int m_blk = ((id & 7) << 3) | ((id >> 3) & 7);
  const int n0 = n_blk << 8;
  const int m0 = m_blk << 7;
  const short* A = (n0 < CDIM) ? Xq : Xkv;      // 512 % 256 == 0: no straddle
  const int t = threadIdx.x;
  const int w = t >> 6, l = t & 63;
  const int wm = w & 1, wn = w >> 1;
  const int lc = l & 15, lr = l >> 4;

  f32x4 acc[4][8];
#pragma unroll
  for (int i = 0; i < 4; ++i)
#pragma unroll
    for (int j = 0; j < 8; ++j) acc[i][j] = (f32x4){0.f, 0.f, 0.f, 0.f};

  for (int kb = 0; kb < 8; ++kb) {
    const int k0 = kb * 64;
#pragma unroll
    for (int i = 0; i < 4; ++i) {               // A: 1024 slots
      const int Qi = (w * 4 + i) * 64 + l;
      const int row = Qi >> 3, u = Qi & 7;
      GLOAD_LDS16(A + (size_t)(m0 + row) * CDIM + k0 + ((u ^ (row & 7)) * 8), &Asm[Qi * 8]);
    }
#pragma unroll
    for (int i = 0; i < 8; ++i) {               // B: 2048 slots
      const int Qi = (w * 8 + i) * 64 + l;
      const int row = Qi >> 3, u = Qi & 7;
      GLOAD_LDS16(Wt + (size_t)(n0 + row) * CDIM + k0 + ((u ^ (row & 7)) * 8), &Bsm[Qi * 8]);
    }
    __syncthreads();
#pragma unroll
    for (int kc = 0; kc < 2; ++kc) {
      short8 af[4], bfr[8];
#pragma unroll
      for (int mt = 0; mt < 4; ++mt) {
        const int row = wm * 64 + mt * 16 + lc;
        af[mt] = *(const short8*)(&Asm[(row * 8 + ((kc * 4 + lr) ^ (row & 7))) * 8]);
      }
#pragma unroll
      for (int nt = 0; nt < 8; ++nt) {
        const int row = wn * 128 + nt * 16 + lc;
        bfr[nt] = *(const short8*)(&Bsm[(row * 8 + ((kc * 4 + lr) ^ (row & 7))) * 8]);
      }
#pragma unroll
      for (int mt = 0; mt < 4; ++mt)
#pragma unroll
        for (int nt = 0; nt < 8; ++nt)
          acc[mt][nt] = MFMA16(af[mt], bfr[nt], acc[mt][nt]);
    }
    __syncthreads();
  }

  // ---- epilogue: wave covers 64 m x 128 n = two 64-col head-groups ----
  const int M0 = m0 + wm * 64;
  const int bb = M0 >> 10, s0 = M0 & 1023;
  const int N0 = n0 + wn * 128;
  float bv[8];
#pragma unroll
  for (int nt = 0; nt < 8; ++nt) bv[nt] = bias[N0 + nt * 16 + lc];
  short* slab = epi + w * 1152;

#pragma unroll
  for (int hi = 0; hi < 2; ++hi) {
    const int hg = (N0 >> 6) + hi;
    const int part = hg >> 3, hh = hg & 7;
    const int nb = hi * 4;
    if (part < 2) {
      const float osc = part ? 1.f : KSCALE;
      short* obase = (part ? Kg : Qg) + (size_t)(bb * 8 + hh) * 65536 + (size_t)s0 * 64;
#pragma unroll
      for (int mt = 0; mt < 4; ++mt) {
#pragma unroll
        for (int ntL = 0; ntL < 4; ++ntL)
#pragma unroll
          for (int r = 0; r < 4; ++r)
            slab[(lr * 4 + r) * 72 + ntL * 16 + lc] =
                f2bf((acc[mt][nb + ntL][r] + bv[nb + ntL]) * osc);
        LDS_FENCE();                            // write -> cross-lane read
#pragma unroll
        for (int i = 0; i < 2; ++i) {
          const int slot = i * 64 + l;
          const int m_l = slot >> 3, n8 = (slot & 7) * 8;
          short8 vv = *(const short8*)(&slab[m_l * 72 + n8]);
          *(short8*)(obase + (size_t)(mt * 16 + m_l) * 64 + n8) = vv;
        }
        LDS_FENCE();                            // read -> next-iter write (WAR)
      }
    } else {
      short* vbase = Vt + (size_t)(bb * 8 + hh) * 65536;
#pragma unroll
      for (int ntL = 0; ntL < 4; ++ntL) {
#pragma unroll
        for (int mt = 0; mt < 4; ++mt)
#pragma unroll
          for (int r = 0; r < 4; ++r)
            slab[lc * 72 + mt * 16 + lr * 4 + r] = f2bf(acc[mt][nb + ntL][r] + bv[nb + ntL]);
        LDS_FENCE();                            // write -> cross-lane read
#pragma unroll
        for (int i = 0; i < 2; ++i) {
          const int slot = i * 64 + l;
          const int dloc = slot >> 3, ch = (slot & 7) * 8;
          short8 vv = *(const short8*)(&slab[dloc * 72 + ch]);
          *(short8*)(vbase + (size_t)(ntL * 16 + dloc) * 1024 + s0 + ch) = vv;
        }
        LDS_FENCE();                            // read -> next-iter write (WAR)
      }
    }
  }
}

// ---- flash attention: 128 q per block; cross-tile double-buffered pipeline
//      (T3/T4): stage tile t+1 while computing tile t, counted vmcnt(4) --
//      never 0 in the main loop -- so K/V fetch latency hides under MFMA+exp2.
//      End-of-tile barrier drains lgkmcnt ONLY (prefetch stays in flight). ----
__global__ __launch_bounds__(256, 2) void flash_attn(const short* __restrict__ Qg,
                                                     const short* __restrict__ Kg,
                                                     const short* __restrict__ Vt,
                                                     float* __restrict__ out) {
  __shared__ alignas(16) short smem[25600];     // 51.2 KB: K 2x8K + V 2x8K + P 9.2K
  short* Ksm = smem;                            // 2 x [64 s][8 swz][8]
  short* Vsm = smem + 8192;                     // 2 x [64 d][8 swz][8]
  const int bh = blockIdx.x;                    // id%8 == h: q-blocks of one bh share XCD
  const int b = bh >> 3, h = bh & 7;
  const int q0 = blockIdx.y * 128;
  const int t = threadIdx.x;
  const int w = t >> 6, l = t & 63;
  const int quad = l >> 4, l15 = l & 15;
  short* Pw = smem + 16384 + w * 2304;          // per-wave, 2 slabs [16 q][72]

  const short* Qbase = Qg + (size_t)bh * 65536;
  const short* Kbase = Kg + (size_t)bh * 65536;
  const short* Vbase = Vt + (size_t)bh * 65536;

  short8 bq[2][2];
#pragma unroll
  for (int qs = 0; qs < 2; ++qs) {
    const short* qrow = Qbase + (size_t)(q0 + qs * 64 + w * 16 + l15) * 64;
    bq[qs][0] = *(const short8*)(qrow + quad * 8);
    bq[qs][1] = *(const short8*)(qrow + 32 + quad * 8);
  }

  float lp[2] = {0.f, 0.f};
  f32x4 Oac[2][4];
#pragma unroll
  for (int qs = 0; qs < 2; ++qs)
#pragma unroll
    for (int dt = 0; dt < 4; ++dt) Oac[qs][dt] = (f32x4){0.f, 0.f, 0.f, 0.f};

  // stage one 64-k tile (4 VMEM ops/thread: 2 K + 2 V) into buffer `buf`
  auto stage_tile = [&](int tile, int buf) {
    const int kk0 = tile * 64;
    short* Kd = Ksm + buf * 4096;
    short* Vd = Vsm + buf * 4096;
#pragma unroll
    for (int i = 0; i < 2; ++i) {
      const int Qi = (w * 2 + i) * 64 + l;
      const int sr = Qi >> 3, u = Qi & 7;
      GLOAD_LDS16(Kbase + (size_t)(kk0 + sr) * 64 + (u ^ (sr & 7)) * 8, &Kd[Qi * 8]);
      GLOAD_LDS16(Vbase + (size_t)sr * 1024 + kk0 + (u ^ (sr & 7)) * 8, &Vd[Qi * 8]);
    }
  };

  stage_tile(0, 0);
  for (int tt = 0; tt < 16; ++tt) {
    const int buf = tt & 1;
    if (tt < 15) {
      stage_tile(tt + 1, buf ^ 1);              // prefetch into the other buffer
      TILE_SYNC(4);                             // tile tt landed; tt+1 in flight
    } else {
      TILE_SYNC(0);                             // epilogue: drain the last tile
    }

    const short* Kh = Ksm + buf * 4096;
    const short* Vh = Vsm + buf * 4096;
    short8 kf[2][4];
#pragma unroll
    for (int c = 0; c < 2; ++c)
#pragma unroll
      for (int nt = 0; nt < 4; ++nt) {
        const int srow = nt * 16 + l15;
        kf[c][nt] = *(const short8*)(&Kh[(srow * 8 + ((c * 4 + quad) ^ (srow & 7))) * 8]);
      }

#pragma unroll
    for (int qs = 0; qs < 2; ++qs) {
      f32x4 st[4];
      __builtin_amdgcn_s_setprio(1);
#pragma unroll
      for (int nt = 0; nt < 4; ++nt) {
        st[nt] = (f32x4){0.f, 0.f, 0.f, 0.f};
#pragma unroll
        for (int c = 0; c < 2; ++c) st[nt] = MFMA16(kf[c][nt], bq[qs][c], st[nt]);
      }
      __builtin_amdgcn_s_setprio(0);
      short* Ps = Pw + qs * 1152;
#pragma unroll
      for (int nt = 0; nt < 4; ++nt) {
        float p0 = __builtin_amdgcn_exp2f(st[nt][0]);
        float p1 = __builtin_amdgcn_exp2f(st[nt][1]);
        float p2 = __builtin_amdgcn_exp2f(st[nt][2]);
        float p3 = __builtin_amdgcn_exp2f(st[nt][3]);
        lp[qs] += (p0 + p1) + (p2 + p3);
        uint2v pk;
        pk[0] = pack_bf16(p0, p1);
        pk[1] = pack_bf16(p2, p3);
        // short-typed store: alias-compatible with the short8 reads below
        *(short4v*)(&Ps[l15 * 72 + (nt * 4 + quad) * 4]) = __builtin_bit_cast(short4v, pk);
      }
    }
    LDS_FENCE();                                // P write -> cross-lane P read

    __builtin_amdgcn_s_setprio(1);
#pragma unroll
    for (int c = 0; c < 2; ++c) {
      short8 pb0 = *(const short8*)(&Pw[l15 * 72 + (c * 8 + quad * 2) * 4]);
      short8 pb1 = *(const short8*)(&Pw[1152 + l15 * 72 + (c * 8 + quad * 2) * 4]);
#pragma unroll
      for (int dt = 0; dt < 4; ++dt) {
        const int drow = dt * 16 + l15;
        short8 vf = *(const short8*)(&Vh[(drow * 8 + ((c * 4 + quad) ^ (drow & 7))) * 8]);
        Oac[0][dt] = MFMA16(vf, pb0, Oac[0][dt]);
        Oac[1][dt] = MFMA16(vf, pb1, Oac[1][dt]);
      }
    }
    __builtin_amdgcn_s_setprio(0);
    TILE_BAR();                                 // lgkm drain + barrier; vmcnt live
  }

#pragma unroll
  for (int qs = 0; qs < 2; ++qs) {
    float lv = lp[qs];
    lv += __shfl_xor(lv, 16, 64);
    lv += __shfl_xor(lv, 32, 64);
    const float rinv = 1.f / lv;
    float* ob = out + ((size_t)(b * 512 + h * 64)) * 1024 + q0 + qs * 64 + w * 16 + l15;
#pragma unroll
    for (int dt = 0; dt < 4; ++dt)
#pragma unroll
      for (int r = 0; r < 4; ++r)
        ob[(size_t)(dt * 16 + quad * 4 + r) * 1024] = Oac[qs][dt][r] * rinv;
  }
}

extern "C" void kernel_launch(void* const* d_in, const int* in_sizes, int n_in,
                              void* d_out, int out_size, void* d_ws, size_t ws_size,
                              hipStream_t stream) {
  const float* query = (const float*)d_in[0];   // f32 [8,512,1024]
  const float* keyv  = (const float*)d_in[1];   // f32 [8,512,1024]
  const float* Wqkv  = (const float*)d_in[2];   // f32 [512,1536]
  const float* bqkv  = (const float*)d_in[3];   // f32 [1536]
  float* out = (float*)d_out;                   // f32 [8,512,1024]
  short* ws  = (short*)d_ws;

  short* Xq_t  = ws;               // bf16 [8192,512]
  short* Xkv_t = ws + 4194304;     // bf16 [8192,512]
  short* W_t   = ws + 8388608;     // bf16 [1536,512]
  short* Qg    = ws + 9175040;     // bf16 [64][1024][64] (pre-scaled)
  short* Kg    = ws + 13369344;    // bf16 [64][1024][64]
  short* Vt    = ws + 17563648;    // bf16 [64][64][1024]

  prep_transpose<<<dim3(2240), 256, 0, stream>>>(query, keyv, Wqkv, Xq_t, Xkv_t, W_t);
  qkv_gemm<<<dim3(384), 256, 0, stream>>>(Xq_t, Xkv_t, W_t, bqkv, Qg, Kg, Vt);
  flash_attn<<<dim3(64, 8, 1), 256, 0, stream>>>(Qg, Kg, Vt, out);
}

// Round 3
// 125.773 us; speedup vs baseline: 1.0568x; 1.0568x over previous
//
#include <hip/hip_runtime.h>
#include <hip/hip_bf16.h>

using short4v = __attribute__((ext_vector_type(4))) short;
using short8  = __attribute__((ext_vector_type(8))) short;
using uint2v  = __attribute__((ext_vector_type(2))) unsigned int;
using f32x4   = __attribute__((ext_vector_type(4))) float;

static constexpr int CDIM = 512;
static constexpr float KSCALE = 0.125f * 1.44269504088896341f;  // scale*log2(e), folded into Q

// proven RNE convert (rounds 2-5)
__device__ __forceinline__ short f2bf(float f) {
  unsigned u = __builtin_bit_cast(unsigned, f);
  u = (u + 0x7fffu + ((u >> 16) & 1u)) >> 16;
  return (short)(unsigned short)u;
}

#define GLOAD_LDS16(gp, lp)                                                              \
  __builtin_amdgcn_global_load_lds((const __attribute__((address_space(1))) void*)(gp),  \
                                   (__attribute__((address_space(3))) void*)(lp), 16, 0, 0)
#define MFMA16(a, b, c) __builtin_amdgcn_mfma_f32_16x16x32_bf16((a), (b), (c), 0, 0, 0)

// Hardened intra-wave LDS fence (rule #18 class): IR fence + lgkmcnt drain +
// machine-scheduler fence.
#define LDS_FENCE()                        \
  do {                                     \
    asm volatile("" ::: "memory");         \
    __builtin_amdgcn_s_waitcnt(0xc07f);    \
    __builtin_amdgcn_sched_barrier(0);     \
  } while (0)

// Pipeline sync (T4): counted vmcnt, never 0 in steady state, then barrier.
#define TILE_SYNC(N)                                          \
  do {                                                        \
    __builtin_amdgcn_sched_barrier(0);                        \
    asm volatile("s_waitcnt vmcnt(" #N ")" ::: "memory");     \
    __builtin_amdgcn_sched_barrier(0);                        \
    __builtin_amdgcn_s_barrier();                             \
    asm volatile("" ::: "memory");                            \
    __builtin_amdgcn_sched_barrier(0);                        \
  } while (0)

// End-of-tile barrier: drain LDS reads only; vmcnt prefetch stays in flight.
#define TILE_BAR()                                            \
  do {                                                        \
    __builtin_amdgcn_sched_barrier(0);                        \
    asm volatile("s_waitcnt lgkmcnt(0)" ::: "memory");        \
    __builtin_amdgcn_sched_barrier(0);                        \
    __builtin_amdgcn_s_barrier();                             \
    asm volatile("" ::: "memory");                            \
    __builtin_amdgcn_sched_barrier(0);                        \
  } while (0)

// ---- fused cast+transpose for Q, KV, W in ONE launch ----
__global__ __launch_bounds__(256) void prep_transpose(const float* __restrict__ query,
                                                      const float* __restrict__ keyv,
                                                      const float* __restrict__ Wqkv,
                                                      short* __restrict__ Xq_t,
                                                      short* __restrict__ Xkv_t,
                                                      short* __restrict__ W_t) {
  __shared__ float tile[64 * 65];
  const int id = blockIdx.x;
  const float* s; short* d; int R, C, r0, c0;
  if (id < 2048) {
    const int which = id >> 10;
    int rem = id & 1023;
    const int b = rem >> 7; rem &= 127;
    R = 512; C = 1024;
    s = (which ? keyv : query) + (size_t)b * 512 * 1024;
    d = (which ? Xkv_t : Xq_t) + (size_t)b * 512 * 1024;
    r0 = (rem >> 4) * 64; c0 = (rem & 15) * 64;
  } else {
    const int rem = id - 2048;                 // 0..191
    R = 512; C = 1536; s = Wqkv; d = W_t;
    r0 = (rem / 24) * 64; c0 = (rem % 24) * 64;
  }
  const int t  = threadIdx.x;
  const int rr = t >> 4;
  const int c4 = (t & 15) * 4;
#pragma unroll
  for (int i = 0; i < 4; ++i) {
    const int r = rr + i * 16;
    f32x4 v = *(const f32x4*)(s + (size_t)(r0 + r) * C + c0 + c4);
#pragma unroll
    for (int j = 0; j < 4; ++j) tile[(c4 + j) * 65 + r] = v[j];
  }
  __syncthreads();
  const int r8 = (t & 7) * 8;
#pragma unroll
  for (int i = 0; i < 2; ++i) {
    const int c = (t >> 3) + i * 32;
    short8 pk;
#pragma unroll
    for (int j = 0; j < 8; ++j) pk[j] = f2bf(tile[c * 65 + r8 + j]);
    *(short8*)(d + (size_t)(c0 + c) * R + r0 + r8) = pk;
  }
}

// ---- QKV projection, BM=128 BN=128 BK=64: 768 blocks = exactly 3/CU,
//      balanced single round, 12 waves/CU for latency hiding. ----
//   Qg,Kg: [bh][s][d] (Q pre-scaled by KSCALE), Vt: [bh][d][s]
__global__ __launch_bounds__(256, 3) void qkv_gemm(const short* __restrict__ Xq,
                                                   const short* __restrict__ Xkv,
                                                   const short* __restrict__ Wt,
                                                   const float* __restrict__ bias,
                                                   short* __restrict__ Qg,
                                                   short* __restrict__ Kg,
                                                   short* __restrict__ Vt) {
  __shared__ short Asm[128 * 64];               // slot(row,u) holds chunk u^(row&7)
  __shared__ short Bsm[128 * 64];
  __shared__ short epi[4 * 1152];
  // XCD clustering (bijective): id&7 = XCD; each XCD owns 8 m-tiles x 12
  // n-tiles -> A slice (1MB) + W (1.5MB) L2-resident per XCD.
  const int id = blockIdx.x;
  const int qq = id >> 3;                       // 0..95
  const int m_blk = ((id & 7) << 3) | (qq & 7); // 0..63
  const int n_blk = qq >> 3;                    // 0..11
  const int m0 = m_blk << 7;
  const int n0 = n_blk << 7;
  const short* A = (n0 < CDIM) ? Xq : Xkv;      // 512 % 128 == 0: no straddle
  const int t = threadIdx.x;
  const int w = t >> 6, l = t & 63;
  const int wm = w & 1, wn = w >> 1;
  const int lc = l & 15, lr = l >> 4;

  f32x4 acc[4][4];
#pragma unroll
  for (int i = 0; i < 4; ++i)
#pragma unroll
    for (int j = 0; j < 4; ++j) acc[i][j] = (f32x4){0.f, 0.f, 0.f, 0.f};

  for (int kb = 0; kb < 8; ++kb) {
    const int k0 = kb * 64;
#pragma unroll
    for (int i = 0; i < 4; ++i) {               // A,B: 1024 slots each
      const int Qi = (w * 4 + i) * 64 + l;
      const int row = Qi >> 3, u = Qi & 7;
      GLOAD_LDS16(A + (size_t)(m0 + row) * CDIM + k0 + ((u ^ (row & 7)) * 8), &Asm[Qi * 8]);
      GLOAD_LDS16(Wt + (size_t)(n0 + row) * CDIM + k0 + ((u ^ (row & 7)) * 8), &Bsm[Qi * 8]);
    }
    __syncthreads();
#pragma unroll
    for (int kc = 0; kc < 2; ++kc) {
      short8 af[4], bfr[4];
#pragma unroll
      for (int mt = 0; mt < 4; ++mt) {
        const int row = wm * 64 + mt * 16 + lc;
        af[mt] = *(const short8*)(&Asm[(row * 8 + ((kc * 4 + lr) ^ (row & 7))) * 8]);
      }
#pragma unroll
      for (int nt = 0; nt < 4; ++nt) {
        const int row = wn * 64 + nt * 16 + lc;
        bfr[nt] = *(const short8*)(&Bsm[(row * 8 + ((kc * 4 + lr) ^ (row & 7))) * 8]);
      }
#pragma unroll
      for (int mt = 0; mt < 4; ++mt)
#pragma unroll
        for (int nt = 0; nt < 4; ++nt)
          acc[mt][nt] = MFMA16(af[mt], bfr[nt], acc[mt][nt]);
    }
    __syncthreads();
  }

  // ---- epilogue: wave covers 64 m x 64 n = exactly one head-group ----
  const int M0 = m0 + wm * 64;
  const int bb = M0 >> 10, s0 = M0 & 1023;
  const int N0 = n0 + wn * 64;
  float bv[4];
#pragma unroll
  for (int nt = 0; nt < 4; ++nt) bv[nt] = bias[N0 + nt * 16 + lc];
  short* slab = epi + w * 1152;

  const int hg = N0 >> 6;
  const int part = hg >> 3, hh = hg & 7;
  if (part < 2) {
    const float osc = part ? 1.f : KSCALE;
    short* obase = (part ? Kg : Qg) + (size_t)(bb * 8 + hh) * 65536 + (size_t)s0 * 64;
#pragma unroll
    for (int mt = 0; mt < 4; ++mt) {
#pragma unroll
      for (int ntL = 0; ntL < 4; ++ntL)
#pragma unroll
        for (int r = 0; r < 4; ++r)
          slab[(lr * 4 + r) * 72 + ntL * 16 + lc] =
              f2bf((acc[mt][ntL][r] + bv[ntL]) * osc);
      LDS_FENCE();                              // write -> cross-lane read
#pragma unroll
      for (int i = 0; i < 2; ++i) {
        const int slot = i * 64 + l;
        const int m_l = slot >> 3, n8 = (slot & 7) * 8;
        short8 vv = *(const short8*)(&slab[m_l * 72 + n8]);
        *(short8*)(obase + (size_t)(mt * 16 + m_l) * 64 + n8) = vv;
      }
      LDS_FENCE();                              // read -> next-iter write (WAR)
    }
  } else {
    short* vbase = Vt + (size_t)(bb * 8 + hh) * 65536;
#pragma unroll
    for (int ntL = 0; ntL < 4; ++ntL) {
#pragma unroll
      for (int mt = 0; mt < 4; ++mt)
#pragma unroll
        for (int r = 0; r < 4; ++r)
          slab[lc * 72 + mt * 16 + lr * 4 + r] = f2bf(acc[mt][ntL][r] + bv[ntL]);
      LDS_FENCE();                              // write -> cross-lane read
#pragma unroll
      for (int i = 0; i < 2; ++i) {
        const int slot = i * 64 + l;
        const int dloc = slot >> 3, ch = (slot & 7) * 8;
        short8 vv = *(const short8*)(&slab[dloc * 72 + ch]);
        *(short8*)(vbase + (size_t)(ntL * 16 + dloc) * 1024 + s0 + ch) = vv;
      }
      LDS_FENCE();                              // read -> next-iter write (WAR)
    }
  }
}

// ---- flash attention: 128 q per block; cross-tile double-buffered pipeline
//      (T3/T4), counted vmcnt(4); P pack via v_cvt_pk_bf16_f32 (T12) ----
__global__ __launch_bounds__(256, 2) void flash_attn(const short* __restrict__ Qg,
                                                     const short* __restrict__ Kg,
                                                     const short* __restrict__ Vt,
                                                     float* __restrict__ out) {
  __shared__ alignas(16) short smem[25600];     // 51.2 KB: K 2x8K + V 2x8K + P 9.2K
  short* Ksm = smem;                            // 2 x [64 s][8 swz][8]
  short* Vsm = smem + 8192;                     // 2 x [64 d][8 swz][8]
  const int bh = blockIdx.x;                    // id%8 == h: q-blocks of one bh share XCD
  const int b = bh >> 3, h = bh & 7;
  const int q0 = blockIdx.y * 128;
  const int t = threadIdx.x;
  const int w = t >> 6, l = t & 63;
  const int quad = l >> 4, l15 = l & 15;
  short* Pw = smem + 16384 + w * 2304;          // per-wave, 2 slabs [16 q][72]

  const short* Qbase = Qg + (size_t)bh * 65536;
  const short* Kbase = Kg + (size_t)bh * 65536;
  const short* Vbase = Vt + (size_t)bh * 65536;

  short8 bq[2][2];
#pragma unroll
  for (int qs = 0; qs < 2; ++qs) {
    const short* qrow = Qbase + (size_t)(q0 + qs * 64 + w * 16 + l15) * 64;
    bq[qs][0] = *(const short8*)(qrow + quad * 8);
    bq[qs][1] = *(const short8*)(qrow + 32 + quad * 8);
  }

  float lp[2] = {0.f, 0.f};
  f32x4 Oac[2][4];
#pragma unroll
  for (int qs = 0; qs < 2; ++qs)
#pragma unroll
    for (int dt = 0; dt < 4; ++dt) Oac[qs][dt] = (f32x4){0.f, 0.f, 0.f, 0.f};

  // stage one 64-k tile (4 VMEM ops/thread: 2 K + 2 V) into buffer `buf`
  auto stage_tile = [&](int tile, int buf) {
    const int kk0 = tile * 64;
    short* Kd = Ksm + buf * 4096;
    short* Vd = Vsm + buf * 4096;
#pragma unroll
    for (int i = 0; i < 2; ++i) {
      const int Qi = (w * 2 + i) * 64 + l;
      const int sr = Qi >> 3, u = Qi & 7;
      GLOAD_LDS16(Kbase + (size_t)(kk0 + sr) * 64 + (u ^ (sr & 7)) * 8, &Kd[Qi * 8]);
      GLOAD_LDS16(Vbase + (size_t)sr * 1024 + kk0 + (u ^ (sr & 7)) * 8, &Vd[Qi * 8]);
    }
  };

  stage_tile(0, 0);
  for (int tt = 0; tt < 16; ++tt) {
    const int buf = tt & 1;
    if (tt < 15) {
      stage_tile(tt + 1, buf ^ 1);              // prefetch into the other buffer
      TILE_SYNC(4);                             // tile tt landed; tt+1 in flight
    } else {
      TILE_SYNC(0);                             // epilogue: drain the last tile
    }

    const short* Kh = Ksm + buf * 4096;
    const short* Vh = Vsm + buf * 4096;
    short8 kf[2][4];
#pragma unroll
    for (int c = 0; c < 2; ++c)
#pragma unroll
      for (int nt = 0; nt < 4; ++nt) {
        const int srow = nt * 16 + l15;
        kf[c][nt] = *(const short8*)(&Kh[(srow * 8 + ((c * 4 + quad) ^ (srow & 7))) * 8]);
      }

#pragma unroll
    for (int qs = 0; qs < 2; ++qs) {
      f32x4 st[4];
      __builtin_amdgcn_s_setprio(1);
#pragma unroll
      for (int nt = 0; nt < 4; ++nt) {
        st[nt] = (f32x4){0.f, 0.f, 0.f, 0.f};
#pragma unroll
        for (int c = 0; c < 2; ++c) st[nt] = MFMA16(kf[c][nt], bq[qs][c], st[nt]);
      }
      __builtin_amdgcn_s_setprio(0);
      short* Ps = Pw + qs * 1152;
#pragma unroll
      for (int nt = 0; nt < 4; ++nt) {
        float p0 = __builtin_amdgcn_exp2f(st[nt][0]);
        float p1 = __builtin_amdgcn_exp2f(st[nt][1]);
        float p2 = __builtin_amdgcn_exp2f(st[nt][2]);
        float p3 = __builtin_amdgcn_exp2f(st[nt][3]);
        lp[qs] += (p0 + p1) + (p2 + p3);
        unsigned pk0, pk1;                      // T12: 1 instr per bf16 pair
        asm("v_cvt_pk_bf16_f32 %0, %1, %2" : "=v"(pk0) : "v"(p0), "v"(p1));
        asm("v_cvt_pk_bf16_f32 %0, %1, %2" : "=v"(pk1) : "v"(p2), "v"(p3));
        uint2v pk; pk[0] = pk0; pk[1] = pk1;
        // short-typed store: alias-compatible with the short8 reads below
        *(short4v*)(&Ps[l15 * 72 + (nt * 4 + quad) * 4]) = __builtin_bit_cast(short4v, pk);
      }
    }
    LDS_FENCE();                                // P write -> cross-lane P read

    __builtin_amdgcn_s_setprio(1);
#pragma unroll
    for (int c = 0; c < 2; ++c) {
      short8 pb0 = *(const short8*)(&Pw[l15 * 72 + (c * 8 + quad * 2) * 4]);
      short8 pb1 = *(const short8*)(&Pw[1152 + l15 * 72 + (c * 8 + quad * 2) * 4]);
#pragma unroll
      for (int dt = 0; dt < 4; ++dt) {
        const int drow = dt * 16 + l15;
        short8 vf = *(const short8*)(&Vh[(drow * 8 + ((c * 4 + quad) ^ (drow & 7))) * 8]);
        Oac[0][dt] = MFMA16(vf, pb0, Oac[0][dt]);
        Oac[1][dt] = MFMA16(vf, pb1, Oac[1][dt]);
      }
    }
    __builtin_amdgcn_s_setprio(0);
    TILE_BAR();                                 // lgkm drain + barrier; vmcnt live
  }

#pragma unroll
  for (int qs = 0; qs < 2; ++qs) {
    float lv = lp[qs];
    lv += __shfl_xor(lv, 16, 64);
    lv += __shfl_xor(lv, 32, 64);
    const float rinv = 1.f / lv;
    float* ob = out + ((size_t)(b * 512 + h * 64)) * 1024 + q0 + qs * 64 + w * 16 + l15;
#pragma unroll
    for (int dt = 0; dt < 4; ++dt)
#pragma unroll
      for (int r = 0; r < 4; ++r)
        ob[(size_t)(dt * 16 + quad * 4 + r) * 1024] = Oac[qs][dt][r] * rinv;
  }
}

extern "C" void kernel_launch(void* const* d_in, const int* in_sizes, int n_in,
                              void* d_out, int out_size, void* d_ws, size_t ws_size,
                              hipStream_t stream) {
  const float* query = (const float*)d_in[0];   // f32 [8,512,1024]
  const float* keyv  = (const float*)d_in[1];   // f32 [8,512,1024]
  const float* Wqkv  = (const float*)d_in[2];   // f32 [512,1536]
  const float* bqkv  = (const float*)d_in[3];   // f32 [1536]
  float* out = (float*)d_out;                   // f32 [8,512,1024]
  short* ws  = (short*)d_ws;

  short* Xq_t  = ws;               // bf16 [8192,512]
  short* Xkv_t = ws + 4194304;     // bf16 [8192,512]
  short* W_t   = ws + 8388608;     // bf16 [1536,512]
  short* Qg    = ws + 9175040;     // bf16 [64][1024][64] (pre-scaled)
  short* Kg    = ws + 13369344;    // bf16 [64][1024][64]
  short* Vt    = ws + 17563648;    // bf16 [64][64][1024]

  prep_transpose<<<dim3(2240), 256, 0, stream>>>(query, keyv, Wqkv, Xq_t, Xkv_t, W_t);
  qkv_gemm<<<dim3(768), 256, 0, stream>>>(Xq_t, Xkv_t, W_t, bqkv, Qg, Kg, Vt);
  flash_attn<<<dim3(64, 8, 1), 256, 0, stream>>>(Qg, Kg, Vt, out);
}